// Round 7
// baseline (2957.745 us; speedup 1.0000x reference)
//
#include <hip/hip_runtime.h>

#define H       64
#define NSLOT   4
#define NSTEP   23          // SEQ_LEN - 1
#define NB      65536
#define NV      66          // VOCAB_SIZE + 2
#define SEQL    24
#define LPE     8           // lanes per element
#define TPB     512         // 8 waves
#define EPB     128         // elements per block (G=2 per lane)
#define ACTSTR  68          // act row stride (floats): 16B-aligned, banks shift 4/elem
#define KLM     3           // m < KLM read W1m from LDS; else global
#define W1LROW  24          // LDS W1m row stride (3 chunks of 8)
#define W1LSLOT 1540        // LDS W1m slot stride (+4: shifts banks per slot)

// ---- workspace layout (float offsets) ----
#define OFF_EW1   0                         // embW1b  [NV][H] = embed@W1[:64] + b1
#define OFF_EWR1  (NV * H)                  // embWr1b [NV][H] = embed@Wr1[:64] + br1

__global__ __launch_bounds__(256) void k_setup_tables(
    const float* __restrict__ embed, const float* __restrict__ W1, const float* __restrict__ b1,
    const float* __restrict__ Wr1, const float* __restrict__ br1, float* __restrict__ ws)
{
    int idx = blockIdx.x * 256 + threadIdx.x;
    if (idx >= NV * H) return;
    int t = idx >> 6, k = idx & 63;
    float a1 = b1[k], a2 = br1[k];
    for (int j = 0; j < H; ++j) {
        float e = embed[t * H + j];
        a1 = fmaf(e, W1[j * H + k], a1);
        a2 = fmaf(e, Wr1[j * H + k], a2);
    }
    ws[OFF_EW1 + idx]  = a1;
    ws[OFF_EWR1 + idx] = a2;
}

#define FMA8V(w0, w1, a, ACC) do {                                          \
    ACC[0]=fmaf((a),w0.x,ACC[0]); ACC[1]=fmaf((a),w0.y,ACC[1]);            \
    ACC[2]=fmaf((a),w0.z,ACC[2]); ACC[3]=fmaf((a),w0.w,ACC[3]);            \
    ACC[4]=fmaf((a),w1.x,ACC[4]); ACC[5]=fmaf((a),w1.y,ACC[5]);            \
    ACC[6]=fmaf((a),w1.z,ACC[6]); ACC[7]=fmaf((a),w1.w,ACC[7]);            \
} while (0)

#define LOAD8(ptr, A) do {                                                  \
    const float4* _b = (const float4*)(ptr);                                \
    float4 _b0 = _b[0], _b1 = _b[1];                                        \
    A[0]=_b0.x; A[1]=_b0.y; A[2]=_b0.z; A[3]=_b0.w;                        \
    A[4]=_b1.x; A[5]=_b1.y; A[6]=_b1.z; A[7]=_b1.w;                        \
} while (0)

__global__ __launch_bounds__(TPB, 2) void k_main(
    const float* __restrict__ W1, const float* __restrict__ W2, const float* __restrict__ b2,
    const float* __restrict__ Ww, const float* __restrict__ bw,
    const float* __restrict__ We, const float* __restrict__ be,
    const float* __restrict__ Wr1, const float* __restrict__ Wr2, const float* __restrict__ br2,
    const int* __restrict__ qtok, const int* __restrict__ seqs,
    const float* __restrict__ ws, float* __restrict__ out)
{
    __shared__ float sW2[H * H];             // broadcast reads (same addr across groups)
    __shared__ float sWw[H * H];
    __shared__ float sW1m[NSLOT * W1LSLOT];  // k<24 of each slot matrix
    __shared__ float sAct[EPB * ACTSTR];     // [elem][j] rows, b128 broadcast reads
    __shared__ float sWeT[NSLOT * H];        // We transposed [slot][j]

    const int tid  = threadIdx.x;
    const int m    = tid & (LPE - 1);        // chunk id 0..7
    const int g    = tid >> 3;               // group 0..63 (8 lanes, same wave)
    const int eA   = g;
    const int eB   = g + 64;
    const int gidA = blockIdx.x * EPB + eA;
    const int gidB = blockIdx.x * EPB + eB;
    const int k0   = m * 8;
    const int slot = m & 3;

    // ---- stage weights into LDS ----
    for (int i = tid; i < H * H; i += TPB) { sW2[i] = W2[i]; sWw[i] = Ww[i]; }
    if (tid < NSLOT * H * H / 16) {          // 1024 threads-worth? no: rows below
    }
    // W1m rows: 256 rows (4 slots x 64 j), k<24 each
    if (tid < 256) {
        int s = tid >> 6, j = tid & 63;
        const float* src = W1 + (H + s * H + j) * H;
        float* dst = sW1m + s * W1LSLOT + j * W1LROW;
#pragma unroll
        for (int k = 0; k < KLM * 8; ++k) dst[k] = src[k];
    }
    if (tid < NSLOT * H) {                   // We [j][s] -> sWeT [s][j]
        int j = tid >> 2, s = tid & 3;
        sWeT[s * H + j] = We[j * NSLOT + s];
    }
    __syncthreads();

    const float* embW1b  = ws + OFF_EW1;
    const float* embWr1b = ws + OFF_EWR1;

    float mA0[8], mA1[8], mA2[8], mA3[8], cA[8];
    float mB0[8], mB1[8], mB2[8], mB3[8], cB[8];
#pragma unroll
    for (int i = 0; i < 8; ++i) {
        mA0[i]=0.f; mA1[i]=0.f; mA2[i]=0.f; mA3[i]=0.f; cA[i]=0.f;
        mB0[i]=0.f; mB1[i]=0.f; mB2[i]=0.f; mB3[i]=0.f; cB[i]=0.f;
    }

    float b2r[8], bwr[8];
    LOAD8(b2 + k0, b2r);
    LOAD8(bw + k0, bwr);
    const float bes = be[slot];

    int tokA = seqs[gidA * SEQL];
    int tokB = seqs[gidB * SEQL];

    float accA[8], accB[8];
    float* rowA = sAct + eA * ACTSTR;
    float* rowB = sAct + eB * ACTSTR;

#pragma unroll 1
    for (int t = 0; t < NSTEP; ++t) {
        int tokAn = seqs[gidA * SEQL + t + 1];
        int tokBn = seqs[gidB * SEQL + t + 1];

        // h1 = relu(embW1b[tok] + contrib) -> sAct rows
        {
            float hA[8], hB[8];
            LOAD8(embW1b + tokA * H + k0, hA);
            LOAD8(embW1b + tokB * H + k0, hB);
#pragma unroll
            for (int i = 0; i < 8; ++i) {
                rowA[k0 + i] = fmaxf(hA[i] + cA[i], 0.f);
                rowB[k0 + i] = fmaxf(hB[i] + cB[i], 0.f);
            }
        }

        // h2 = relu(h1 @ W2 + b2)   (W2 via LDS broadcast)
#pragma unroll
        for (int i = 0; i < 8; ++i) { accA[i] = b2r[i]; accB[i] = b2r[i]; }
#pragma unroll 4
        for (int jq = 0; jq < 16; ++jq) {
            float4 a4 = *(const float4*)(rowA + jq * 4);
            float4 b4 = *(const float4*)(rowB + jq * 4);
            float aAv[4] = {a4.x, a4.y, a4.z, a4.w};
            float aBv[4] = {b4.x, b4.y, b4.z, b4.w};
#pragma unroll
            for (int jj = 0; jj < 4; ++jj) {
                const float4* w = (const float4*)(sW2 + (jq * 4 + jj) * H + k0);
                float4 w0 = w[0], w1 = w[1];
                FMA8V(w0, w1, aAv[jj], accA);
                FMA8V(w0, w1, aBv[jj], accB);
            }
        }
#pragma unroll
        for (int i = 0; i < 8; ++i) {
            rowA[k0 + i] = fmaxf(accA[i], 0.f);
            rowB[k0 + i] = fmaxf(accB[i], 0.f);
        }

        // write_vec = h2 @ Ww + bw ; evict logit for slot (m&3)
        float lgA = bes, lgB = bes;
#pragma unroll
        for (int i = 0; i < 8; ++i) { accA[i] = bwr[i]; accB[i] = bwr[i]; }
#pragma unroll 4
        for (int jq = 0; jq < 16; ++jq) {
            float4 a4 = *(const float4*)(rowA + jq * 4);
            float4 b4 = *(const float4*)(rowB + jq * 4);
            float4 we4 = *(const float4*)(sWeT + slot * H + jq * 4);
            float aAv[4] = {a4.x, a4.y, a4.z, a4.w};
            float aBv[4] = {b4.x, b4.y, b4.z, b4.w};
            float wev[4] = {we4.x, we4.y, we4.z, we4.w};
#pragma unroll
            for (int jj = 0; jj < 4; ++jj) {
                const float4* w = (const float4*)(sWw + (jq * 4 + jj) * H + k0);
                float4 w0 = w[0], w1 = w[1];
                FMA8V(w0, w1, aAv[jj], accA);
                FMA8V(w0, w1, aBv[jj], accB);
                lgA = fmaf(aAv[jj], wev[jj], lgA);
                lgB = fmaf(aBv[jj], wev[jj], lgB);
            }
        }

        // argmax per element (lanes base..base+3 hold slots 0..3)
        int base = (tid & 63) & ~(LPE - 1);
        float vA0 = __shfl(lgA, base + 0), vA1 = __shfl(lgA, base + 1);
        float vA2 = __shfl(lgA, base + 2), vA3 = __shfl(lgA, base + 3);
        float vB0 = __shfl(lgB, base + 0), vB1 = __shfl(lgB, base + 1);
        float vB2 = __shfl(lgB, base + 2), vB3 = __shfl(lgB, base + 3);
        int eSA = 0; float bstA = vA0;
        if (vA1 > bstA) { bstA = vA1; eSA = 1; }
        if (vA2 > bstA) { bstA = vA2; eSA = 2; }
        if (vA3 > bstA) { bstA = vA3; eSA = 3; }
        int eSB = 0; float bstB = vB0;
        if (vB1 > bstB) { bstB = vB1; eSB = 1; }
        if (vB2 > bstB) { bstB = vB2; eSB = 2; }
        if (vB3 > bstB) { bstB = vB3; eSB = 3; }

        // mem[e] <- write_vec ; delta -> sAct rows
        {
            bool a0 = (eSA == 0), a1 = (eSA == 1), a2 = (eSA == 2), a3 = (eSA == 3);
            bool b0 = (eSB == 0), b1 = (eSB == 1), b2_ = (eSB == 2), b3 = (eSB == 3);
#pragma unroll
            for (int i = 0; i < 8; ++i) {
                float oldA = a0 ? mA0[i] : a1 ? mA1[i] : a2 ? mA2[i] : mA3[i];
                float oldB = b0 ? mB0[i] : b1 ? mB1[i] : b2_ ? mB2[i] : mB3[i];
                float wA = accA[i], wB = accB[i];
                mA0[i] = a0 ? wA : mA0[i];  mA1[i] = a1 ? wA : mA1[i];
                mA2[i] = a2 ? wA : mA2[i];  mA3[i] = a3 ? wA : mA3[i];
                mB0[i] = b0 ? wB : mB0[i];  mB1[i] = b1 ? wB : mB1[i];
                mB2[i] = b2_ ? wB : mB2[i]; mB3[i] = b3 ? wB : mB3[i];
                rowA[k0 + i] = wA - oldA;
                rowB[k0 + i] = wB - oldB;
            }
        }

        // contrib += delta @ W1mem_e : lanes m<KLM read LDS copy, others global (VMEM).
        const float* lA = sW1m + eSA * W1LSLOT + k0;          // valid for m<KLM
        const float* lB = sW1m + eSB * W1LSLOT + k0;
        const float* gA = W1 + (size_t)(H + eSA * H) * H + k0; // global rows
        const float* gB = W1 + (size_t)(H + eSB * H) * H + k0;
#pragma unroll 4
        for (int jq = 0; jq < 16; ++jq) {
            float4 a4 = *(const float4*)(rowA + jq * 4);
            float4 b4 = *(const float4*)(rowB + jq * 4);
            float dAv[4] = {a4.x, a4.y, a4.z, a4.w};
            float dBv[4] = {b4.x, b4.y, b4.z, b4.w};
#pragma unroll
            for (int jj = 0; jj < 4; ++jj) {
                int j = jq * 4 + jj;
                float4 w0A, w1A, w0B, w1B;
                if (m < KLM) {
                    const float4* wa = (const float4*)(lA + j * W1LROW);
                    const float4* wb = (const float4*)(lB + j * W1LROW);
                    w0A = wa[0]; w1A = wa[1];
                    w0B = wb[0]; w1B = wb[1];
                } else {
                    const float4* wa = (const float4*)(gA + j * H);
                    const float4* wb = (const float4*)(gB + j * H);
                    w0A = wa[0]; w1A = wa[1];
                    w0B = wb[0]; w1B = wb[1];
                }
                FMA8V(w0A, w1A, dAv[jj], cA);
                FMA8V(w0B, w1B, dBv[jj], cB);
            }
        }

        tokA = tokAn; tokB = tokBn;
    }

    // ---- read head ----
#pragma unroll
    for (int i = 0; i < 8; ++i) {
        rowA[k0 + i] = 0.25f * (mA0[i] + mA1[i] + mA2[i] + mA3[i]);
        rowB[k0 + i] = 0.25f * (mB0[i] + mB1[i] + mB2[i] + mB3[i]);
    }

    int qA = qtok[gidA], qB = qtok[gidB];
    LOAD8(embWr1b + qA * H + k0, accA);
    LOAD8(embWr1b + qB * H + k0, accB);
#pragma unroll 4
    for (int jq = 0; jq < 16; ++jq) {
        float4 a4 = *(const float4*)(rowA + jq * 4);
        float4 b4 = *(const float4*)(rowB + jq * 4);
        float aAv[4] = {a4.x, a4.y, a4.z, a4.w};
        float aBv[4] = {b4.x, b4.y, b4.z, b4.w};
#pragma unroll
        for (int jj = 0; jj < 4; ++jj) {
            const float4* w = (const float4*)(Wr1 + (H + jq * 4 + jj) * H + k0);
            float4 w0 = w[0], w1 = w[1];
            FMA8V(w0, w1, aAv[jj], accA);
            FMA8V(w0, w1, aBv[jj], accB);
        }
    }
#pragma unroll
    for (int i = 0; i < 8; ++i) {
        rowA[k0 + i] = fmaxf(accA[i], 0.f);
        rowB[k0 + i] = fmaxf(accB[i], 0.f);
    }

    LOAD8(br2 + k0, accA);
#pragma unroll
    for (int i = 0; i < 8; ++i) accB[i] = accA[i];
#pragma unroll 4
    for (int jq = 0; jq < 16; ++jq) {
        float4 a4 = *(const float4*)(rowA + jq * 4);
        float4 b4 = *(const float4*)(rowB + jq * 4);
        float aAv[4] = {a4.x, a4.y, a4.z, a4.w};
        float aBv[4] = {b4.x, b4.y, b4.z, b4.w};
#pragma unroll
        for (int jj = 0; jj < 4; ++jj) {
            const float4* w = (const float4*)(Wr2 + (jq * 4 + jj) * H + k0);
            float4 w0 = w[0], w1 = w[1];
            FMA8V(w0, w1, aAv[jj], accA);
            FMA8V(w0, w1, aBv[jj], accB);
        }
    }

    float4* oA = (float4*)(out + (size_t)gidA * H + k0);
    oA[0] = make_float4(accA[0], accA[1], accA[2], accA[3]);
    oA[1] = make_float4(accA[4], accA[5], accA[6], accA[7]);
    float4* oB = (float4*)(out + (size_t)gidB * H + k0);
    oB[0] = make_float4(accB[0], accB[1], accB[2], accB[3]);
    oB[1] = make_float4(accB[4], accB[5], accB[6], accB[7]);
}

extern "C" void kernel_launch(void* const* d_in, const int* in_sizes, int n_in,
                              void* d_out, int out_size, void* d_ws, size_t ws_size,
                              hipStream_t stream)
{
    const int*   seqs  = (const int*)d_in[0];
    const int*   qtok  = (const int*)d_in[1];
    const float* embed = (const float*)d_in[2];
    const float* W1    = (const float*)d_in[3];
    const float* b1    = (const float*)d_in[4];
    const float* W2    = (const float*)d_in[5];
    const float* b2    = (const float*)d_in[6];
    const float* Ww    = (const float*)d_in[7];
    const float* bw    = (const float*)d_in[8];
    const float* We    = (const float*)d_in[9];
    const float* be    = (const float*)d_in[10];
    const float* Wr1   = (const float*)d_in[11];
    const float* br1   = (const float*)d_in[12];
    const float* Wr2   = (const float*)d_in[13];
    const float* br2   = (const float*)d_in[14];
    float* out = (float*)d_out;
    float* ws  = (float*)d_ws;

    hipLaunchKernelGGL(k_setup_tables, dim3((NV * H + 255) / 256), dim3(256), 0, stream,
                       embed, W1, b1, Wr1, br1, ws);
    hipLaunchKernelGGL(k_main, dim3(NB / EPB), dim3(TPB), 0, stream,
                       W1, W2, b2, Ww, bw, We, be, Wr1, Wr2, br2, qtok, seqs, ws, out);
}

// Round 8
// 1010.617 us; speedup vs baseline: 2.9267x; 2.9267x over previous
//
#include <hip/hip_runtime.h>

#define H       64
#define NSLOT   4
#define NSTEP   23          // SEQ_LEN - 1
#define NB      65536
#define NV      66          // VOCAB_SIZE + 2
#define SEQL    24
#define LPE     8           // lanes per element
#define TPB     512         // 8 waves
#define EPB     128         // elements per block (G=2 per lane)
#define ACTSTR  68          // act row stride: 16B-aligned, bank shift 4/row -> conflict-free b128 reads
#define W1RSTR  68          // sW1m row stride
#define W1SSTR  (64 * W1RSTR + 4)   // 4356 ≡ 4 (mod 32): slot shifts miss the m*8 quad pattern

// ---- workspace layout (float offsets) ----
#define OFF_EW1   0                         // embW1b  [NV][H] = embed@W1[:64] + b1
#define OFF_EWR1  (NV * H)                  // embWr1b [NV][H] = embed@Wr1[:64] + br1

__global__ __launch_bounds__(256) void k_setup_tables(
    const float* __restrict__ embed, const float* __restrict__ W1, const float* __restrict__ b1,
    const float* __restrict__ Wr1, const float* __restrict__ br1, float* __restrict__ ws)
{
    int idx = blockIdx.x * 256 + threadIdx.x;
    if (idx >= NV * H) return;
    int t = idx >> 6, k = idx & 63;
    float a1 = b1[k], a2 = br1[k];
    for (int j = 0; j < H; ++j) {
        float e = embed[t * H + j];
        a1 = fmaf(e, W1[j * H + k], a1);
        a2 = fmaf(e, Wr1[j * H + k], a2);
    }
    ws[OFF_EW1 + idx]  = a1;
    ws[OFF_EWR1 + idx] = a2;
}

#define FMA8V(w0, w1, a, ACC) do {                                          \
    ACC[0]=fmaf((a),w0.x,ACC[0]); ACC[1]=fmaf((a),w0.y,ACC[1]);            \
    ACC[2]=fmaf((a),w0.z,ACC[2]); ACC[3]=fmaf((a),w0.w,ACC[3]);            \
    ACC[4]=fmaf((a),w1.x,ACC[4]); ACC[5]=fmaf((a),w1.y,ACC[5]);            \
    ACC[6]=fmaf((a),w1.z,ACC[6]); ACC[7]=fmaf((a),w1.w,ACC[7]);            \
} while (0)

#define LOAD8(ptr, A) do {                                                  \
    const float4* _b = (const float4*)(ptr);                                \
    float4 _b0 = _b[0], _b1 = _b[1];                                        \
    A[0]=_b0.x; A[1]=_b0.y; A[2]=_b0.z; A[3]=_b0.w;                        \
    A[4]=_b1.x; A[5]=_b1.y; A[6]=_b1.z; A[7]=_b1.w;                        \
} while (0)

// store 8 floats (registers) to an act row as two b128 writes
#define STORE8(rowptr, A) do {                                              \
    float4* _d = (float4*)(rowptr);                                         \
    _d[0] = make_float4(A[0], A[1], A[2], A[3]);                            \
    _d[1] = make_float4(A[4], A[5], A[6], A[7]);                            \
} while (0)

__global__ __launch_bounds__(TPB, 2) void k_main(
    const float* __restrict__ W1, const float* __restrict__ W2, const float* __restrict__ b2,
    const float* __restrict__ Ww, const float* __restrict__ bw,
    const float* __restrict__ We, const float* __restrict__ be,
    const float* __restrict__ Wr1, const float* __restrict__ Wr2, const float* __restrict__ br2,
    const int* __restrict__ qtok, const int* __restrict__ seqs,
    const float* __restrict__ ws, float* __restrict__ out)
{
    __shared__ float sW1m[NSLOT * W1SSTR];   // W1mem slot matrices (lgkm pipe)
    __shared__ float sAct[EPB * ACTSTR];     // [elem][j] rows -> b128 broadcast reads
    __shared__ float sWeT[NSLOT * H];        // We transposed [slot][j]

    const int tid  = threadIdx.x;
    const int m    = tid & (LPE - 1);        // chunk id 0..7
    const int g    = tid >> 3;               // group 0..63 (8 lanes, same wave)
    const int eA   = g;
    const int eB   = g + 64;
    const int gidA = blockIdx.x * EPB + eA;
    const int gidB = blockIdx.x * EPB + eB;
    const int k0   = m * 8;
    const int slot = m & 3;

    // ---- stage W1mem + WeT into LDS ----
    if (tid < 256) {
        int s = tid >> 6, j = tid & 63;
        const float4* src = (const float4*)(W1 + (size_t)(H + s * H + j) * H);
        float4* dst = (float4*)(sW1m + s * W1SSTR + j * W1RSTR);
#pragma unroll
        for (int k = 0; k < 16; ++k) dst[k] = src[k];
    }
    if (tid < NSLOT * H) {                   // We [j][s] -> sWeT [s][j]
        int j = tid >> 2, s = tid & 3;
        sWeT[s * H + j] = We[j * NSLOT + s];
    }
    __syncthreads();

    const float* embW1b  = ws + OFF_EW1;
    const float* embWr1b = ws + OFF_EWR1;

    float mA0[8], mA1[8], mA2[8], mA3[8], cA[8];
    float mB0[8], mB1[8], mB2[8], mB3[8], cB[8];
#pragma unroll
    for (int i = 0; i < 8; ++i) {
        mA0[i]=0.f; mA1[i]=0.f; mA2[i]=0.f; mA3[i]=0.f; cA[i]=0.f;
        mB0[i]=0.f; mB1[i]=0.f; mB2[i]=0.f; mB3[i]=0.f; cB[i]=0.f;
    }

    float b2r[8], bwr[8];
    LOAD8(b2 + k0, b2r);
    LOAD8(bw + k0, bwr);
    const float bes = be[slot];

    int tokA = seqs[gidA * SEQL];
    int tokB = seqs[gidB * SEQL];

    float accA[8], accB[8];
    float* rowA = sAct + eA * ACTSTR;
    float* rowB = sAct + eB * ACTSTR;

#pragma unroll 1
    for (int t = 0; t < NSTEP; ++t) {
        int tokAn = seqs[gidA * SEQL + t + 1];
        int tokBn = seqs[gidB * SEQL + t + 1];

        // h1 = relu(embW1b[tok] + contrib) -> sAct rows
        {
            float hA[8], hB[8];
            LOAD8(embW1b + tokA * H + k0, hA);
            LOAD8(embW1b + tokB * H + k0, hB);
#pragma unroll
            for (int i = 0; i < 8; ++i) {
                hA[i] = fmaxf(hA[i] + cA[i], 0.f);
                hB[i] = fmaxf(hB[i] + cB[i], 0.f);
            }
            STORE8(rowA + k0, hA);
            STORE8(rowB + k0, hB);
        }

        // h2 = relu(h1 @ W2 + b2)   (W2 via VMEM; act via b128 LDS broadcast)
#pragma unroll
        for (int i = 0; i < 8; ++i) { accA[i] = b2r[i]; accB[i] = b2r[i]; }
#pragma unroll 4
        for (int jq = 0; jq < 16; ++jq) {
            float4 a4 = *(const float4*)(rowA + jq * 4);
            float4 b4 = *(const float4*)(rowB + jq * 4);
            float aAv[4] = {a4.x, a4.y, a4.z, a4.w};
            float aBv[4] = {b4.x, b4.y, b4.z, b4.w};
#pragma unroll
            for (int jj = 0; jj < 4; ++jj) {
                const float4* w = (const float4*)(W2 + (jq * 4 + jj) * H + k0);
                float4 w0 = w[0], w1 = w[1];
                FMA8V(w0, w1, aAv[jj], accA);
                FMA8V(w0, w1, aBv[jj], accB);
            }
        }
        {
            float hA[8], hB[8];
#pragma unroll
            for (int i = 0; i < 8; ++i) {
                hA[i] = fmaxf(accA[i], 0.f);
                hB[i] = fmaxf(accB[i], 0.f);
            }
            STORE8(rowA + k0, hA);
            STORE8(rowB + k0, hB);
        }

        // write_vec = h2 @ Ww + bw ; evict logit for slot (m&3)
        float lgA = bes, lgB = bes;
#pragma unroll
        for (int i = 0; i < 8; ++i) { accA[i] = bwr[i]; accB[i] = bwr[i]; }
#pragma unroll 4
        for (int jq = 0; jq < 16; ++jq) {
            float4 a4 = *(const float4*)(rowA + jq * 4);
            float4 b4 = *(const float4*)(rowB + jq * 4);
            float4 we4 = *(const float4*)(sWeT + slot * H + jq * 4);
            float aAv[4] = {a4.x, a4.y, a4.z, a4.w};
            float aBv[4] = {b4.x, b4.y, b4.z, b4.w};
            float wev[4] = {we4.x, we4.y, we4.z, we4.w};
#pragma unroll
            for (int jj = 0; jj < 4; ++jj) {
                const float4* w = (const float4*)(Ww + (jq * 4 + jj) * H + k0);
                float4 w0 = w[0], w1 = w[1];
                FMA8V(w0, w1, aAv[jj], accA);
                FMA8V(w0, w1, aBv[jj], accB);
                lgA = fmaf(aAv[jj], wev[jj], lgA);
                lgB = fmaf(aBv[jj], wev[jj], lgB);
            }
        }

        // argmax per element (lanes base..base+3 hold slots 0..3)
        int base = (tid & 63) & ~(LPE - 1);
        float vA0 = __shfl(lgA, base + 0), vA1 = __shfl(lgA, base + 1);
        float vA2 = __shfl(lgA, base + 2), vA3 = __shfl(lgA, base + 3);
        float vB0 = __shfl(lgB, base + 0), vB1 = __shfl(lgB, base + 1);
        float vB2 = __shfl(lgB, base + 2), vB3 = __shfl(lgB, base + 3);
        int eSA = 0; float bstA = vA0;
        if (vA1 > bstA) { bstA = vA1; eSA = 1; }
        if (vA2 > bstA) { bstA = vA2; eSA = 2; }
        if (vA3 > bstA) { bstA = vA3; eSA = 3; }
        int eSB = 0; float bstB = vB0;
        if (vB1 > bstB) { bstB = vB1; eSB = 1; }
        if (vB2 > bstB) { bstB = vB2; eSB = 2; }
        if (vB3 > bstB) { bstB = vB3; eSB = 3; }

        // mem[e] <- write_vec ; delta -> sAct rows
        {
            bool a0 = (eSA == 0), a1 = (eSA == 1), a2 = (eSA == 2), a3 = (eSA == 3);
            bool b0 = (eSB == 0), b1 = (eSB == 1), b2_ = (eSB == 2), b3 = (eSB == 3);
            float dA[8], dB[8];
#pragma unroll
            for (int i = 0; i < 8; ++i) {
                float oldA = a0 ? mA0[i] : a1 ? mA1[i] : a2 ? mA2[i] : mA3[i];
                float oldB = b0 ? mB0[i] : b1 ? mB1[i] : b2_ ? mB2[i] : mB3[i];
                float wA = accA[i], wB = accB[i];
                mA0[i] = a0 ? wA : mA0[i];  mA1[i] = a1 ? wA : mA1[i];
                mA2[i] = a2 ? wA : mA2[i];  mA3[i] = a3 ? wA : mA3[i];
                mB0[i] = b0 ? wB : mB0[i];  mB1[i] = b1 ? wB : mB1[i];
                mB2[i] = b2_ ? wB : mB2[i]; mB3[i] = b3 ? wB : mB3[i];
                dA[i] = wA - oldA;
                dB[i] = wB - oldB;
            }
            STORE8(rowA + k0, dA);
            STORE8(rowB + k0, dB);
        }

        // contrib += delta @ W1mem_e  (LDS, slot stride bank-fixed; no divergence)
        const float* lA = sW1m + eSA * W1SSTR + k0;
        const float* lB = sW1m + eSB * W1SSTR + k0;
#pragma unroll 4
        for (int jq = 0; jq < 16; ++jq) {
            float4 a4 = *(const float4*)(rowA + jq * 4);
            float4 b4 = *(const float4*)(rowB + jq * 4);
            float dAv[4] = {a4.x, a4.y, a4.z, a4.w};
            float dBv[4] = {b4.x, b4.y, b4.z, b4.w};
#pragma unroll
            for (int jj = 0; jj < 4; ++jj) {
                int j = jq * 4 + jj;
                const float4* wa = (const float4*)(lA + j * W1RSTR);
                const float4* wb = (const float4*)(lB + j * W1RSTR);
                float4 wa0 = wa[0], wa1 = wa[1];
                float4 wb0 = wb[0], wb1 = wb[1];
                FMA8V(wa0, wa1, dAv[jj], cA);
                FMA8V(wb0, wb1, dBv[jj], cB);
            }
        }

        tokA = tokAn; tokB = tokBn;
    }

    // ---- read head ----
    {
        float sA[8], sB[8];
#pragma unroll
        for (int i = 0; i < 8; ++i) {
            sA[i] = 0.25f * (mA0[i] + mA1[i] + mA2[i] + mA3[i]);
            sB[i] = 0.25f * (mB0[i] + mB1[i] + mB2[i] + mB3[i]);
        }
        STORE8(rowA + k0, sA);
        STORE8(rowB + k0, sB);
    }

    int qA = qtok[gidA], qB = qtok[gidB];
    LOAD8(embWr1b + qA * H + k0, accA);
    LOAD8(embWr1b + qB * H + k0, accB);
#pragma unroll 4
    for (int jq = 0; jq < 16; ++jq) {
        float4 a4 = *(const float4*)(rowA + jq * 4);
        float4 b4 = *(const float4*)(rowB + jq * 4);
        float aAv[4] = {a4.x, a4.y, a4.z, a4.w};
        float aBv[4] = {b4.x, b4.y, b4.z, b4.w};
#pragma unroll
        for (int jj = 0; jj < 4; ++jj) {
            const float4* w = (const float4*)(Wr1 + (H + jq * 4 + jj) * H + k0);
            float4 w0 = w[0], w1 = w[1];
            FMA8V(w0, w1, aAv[jj], accA);
            FMA8V(w0, w1, aBv[jj], accB);
        }
    }
    {
        float rA[8], rB[8];
#pragma unroll
        for (int i = 0; i < 8; ++i) {
            rA[i] = fmaxf(accA[i], 0.f);
            rB[i] = fmaxf(accB[i], 0.f);
        }
        STORE8(rowA + k0, rA);
        STORE8(rowB + k0, rB);
    }

    LOAD8(br2 + k0, accA);
#pragma unroll
    for (int i = 0; i < 8; ++i) accB[i] = accA[i];
#pragma unroll 4
    for (int jq = 0; jq < 16; ++jq) {
        float4 a4 = *(const float4*)(rowA + jq * 4);
        float4 b4 = *(const float4*)(rowB + jq * 4);
        float aAv[4] = {a4.x, a4.y, a4.z, a4.w};
        float aBv[4] = {b4.x, b4.y, b4.z, b4.w};
#pragma unroll
        for (int jj = 0; jj < 4; ++jj) {
            const float4* w = (const float4*)(Wr2 + (jq * 4 + jj) * H + k0);
            float4 w0 = w[0], w1 = w[1];
            FMA8V(w0, w1, aAv[jj], accA);
            FMA8V(w0, w1, aBv[jj], accB);
        }
    }

    float4* oA = (float4*)(out + (size_t)gidA * H + k0);
    oA[0] = make_float4(accA[0], accA[1], accA[2], accA[3]);
    oA[1] = make_float4(accA[4], accA[5], accA[6], accA[7]);
    float4* oB = (float4*)(out + (size_t)gidB * H + k0);
    oB[0] = make_float4(accB[0], accB[1], accB[2], accB[3]);
    oB[1] = make_float4(accB[4], accB[5], accB[6], accB[7]);
}

extern "C" void kernel_launch(void* const* d_in, const int* in_sizes, int n_in,
                              void* d_out, int out_size, void* d_ws, size_t ws_size,
                              hipStream_t stream)
{
    const int*   seqs  = (const int*)d_in[0];
    const int*   qtok  = (const int*)d_in[1];
    const float* embed = (const float*)d_in[2];
    const float* W1    = (const float*)d_in[3];
    const float* b1    = (const float*)d_in[4];
    const float* W2    = (const float*)d_in[5];
    const float* b2    = (const float*)d_in[6];
    const float* Ww    = (const float*)d_in[7];
    const float* bw    = (const float*)d_in[8];
    const float* We    = (const float*)d_in[9];
    const float* be    = (const float*)d_in[10];
    const float* Wr1   = (const float*)d_in[11];
    const float* br1   = (const float*)d_in[12];
    const float* Wr2   = (const float*)d_in[13];
    const float* br2   = (const float*)d_in[14];
    float* out = (float*)d_out;
    float* ws  = (float*)d_ws;

    hipLaunchKernelGGL(k_setup_tables, dim3((NV * H + 255) / 256), dim3(256), 0, stream,
                       embed, W1, b1, Wr1, br1, ws);
    hipLaunchKernelGGL(k_main, dim3(NB / EPB), dim3(TPB), 0, stream,
                       W1, W2, b2, Ww, bw, We, be, Wr1, Wr2, br2, qtok, seqs, ws, out);
}